// Round 2
// baseline (577.026 us; speedup 1.0000x reference)
//
#include <hip/hip_runtime.h>
#include <hip/hip_bf16.h>

// Householder reflection, row-wise over [B=16384, L=4096] fp32:
//   out[b, :] = z[b, :] - 2 * v[b, :] * (v[b]·z[b]) / (v[b]·v[b])
//
// R1 lesson: with default regalloc the compiler chose 32 VGPRs (max occupancy),
// which (a) re-loaded v/z in the epilogue and (b) capped memory-level
// parallelism at ~2 outstanding loads/wave -> 2.8 TB/s, latency-bound.
// Fix: opaque asm fences pin all 8 float4 loads in registers, issued
// back-to-back -> 8 outstanding 16B loads/wave, zero epilogue re-read.

#define L 4096
#define BLOCK 256
#define VPT (L / (BLOCK * 4))  // 4 float4 per thread per array

// Opaque register fence: compiler must materialize x in VGPRs here and
// cannot rematerialize (re-load) it later.
__device__ __forceinline__ void pin4(float4& x) {
    asm volatile("" : "+v"(x.x), "+v"(x.y), "+v"(x.z), "+v"(x.w));
}

__global__ __launch_bounds__(BLOCK) void hh_kernel(
    const float* __restrict__ v,
    const float* __restrict__ z,
    float* __restrict__ out)
{
    const int b   = blockIdx.x;
    const int tid = threadIdx.x;
    const long long base = (long long)b * L;

    const float4* v4 = reinterpret_cast<const float4*>(v + base);
    const float4* z4 = reinterpret_cast<const float4*>(z + base);
    float4*       o4 = reinterpret_cast<float4*>(out + base);

    float4 vr[VPT];
    float4 zr[VPT];

    // Issue ALL loads first: 8 outstanding float4 loads per lane.
#pragma unroll
    for (int i = 0; i < VPT; ++i) vr[i] = v4[tid + i * BLOCK];
#pragma unroll
    for (int i = 0; i < VPT; ++i) zr[i] = z4[tid + i * BLOCK];
    // Pin them: no remat, no epilogue re-load.
#pragma unroll
    for (int i = 0; i < VPT; ++i) pin4(vr[i]);
#pragma unroll
    for (int i = 0; i < VPT; ++i) pin4(zr[i]);

    float dot = 0.0f;  // v·z partial
    float nsq = 0.0f;  // v·v partial
#pragma unroll
    for (int i = 0; i < VPT; ++i) {
        dot += vr[i].x * zr[i].x + vr[i].y * zr[i].y
             + vr[i].z * zr[i].z + vr[i].w * zr[i].w;
        nsq += vr[i].x * vr[i].x + vr[i].y * vr[i].y
             + vr[i].z * vr[i].z + vr[i].w * vr[i].w;
    }

    // wave-64 butterfly reduction
#pragma unroll
    for (int off = 32; off > 0; off >>= 1) {
        dot += __shfl_down(dot, off, 64);
        nsq += __shfl_down(nsq, off, 64);
    }

    // cross-wave reduction (4 waves per block)
    __shared__ float sdot[BLOCK / 64];
    __shared__ float snsq[BLOCK / 64];
    __shared__ float sscale;
    const int wave = tid >> 6;
    const int lane = tid & 63;
    if (lane == 0) {
        sdot[wave] = dot;
        snsq[wave] = nsq;
    }
    __syncthreads();
    if (tid == 0) {
        float d = 0.0f, n = 0.0f;
#pragma unroll
        for (int w = 0; w < BLOCK / 64; ++w) { d += sdot[w]; n += snsq[w]; }
        sscale = -2.0f * d / n;
    }
    __syncthreads();
    const float s = sscale;

    // Epilogue straight from registers.
#pragma unroll
    for (int i = 0; i < VPT; ++i) {
        float4 o;
        o.x = zr[i].x + s * vr[i].x;
        o.y = zr[i].y + s * vr[i].y;
        o.z = zr[i].z + s * vr[i].z;
        o.w = zr[i].w + s * vr[i].w;
        o4[tid + i * BLOCK] = o;
    }
}

extern "C" void kernel_launch(void* const* d_in, const int* in_sizes, int n_in,
                              void* d_out, int out_size, void* d_ws, size_t ws_size,
                              hipStream_t stream) {
    const float* v = (const float*)d_in[0];
    const float* z = (const float*)d_in[1];
    float* out = (float*)d_out;

    const int B = in_sizes[0] / L;  // 16384
    hh_kernel<<<B, BLOCK, 0, stream>>>(v, z, out);
}